// Round 1
// baseline (258.128 us; speedup 1.0000x reference)
//
#include <hip/hip_runtime.h>
#include <math.h>

#define BB 16
#define HH 512
#define WW 512
#define CC 4

// ---------------------------------------------------------------------------
// Kernel 1: y_s = cumsum_h( 2/(1+exp(-defgrad[...,1])) )  (inclusive, per column)
// grid: BB * (WW/32) blocks; block: 512 threads = 16 h-segments x 32 columns.
// Each thread serially covers 32 rows of one column; segment sums are combined
// through LDS; per-row values are kept in registers (no second global read).
// ---------------------------------------------------------------------------
__global__ __launch_bounds__(512)
void colscan_kernel(const float2* __restrict__ defgrad, float* __restrict__ ys,
                    int ys_stride) {
    const int wt  = blockIdx.x % (WW / 32);
    const int b   = blockIdx.x / (WW / 32);
    const int col = threadIdx.x & 31;
    const int seg = threadIdx.x >> 5;      // 0..15
    const int SEGH = HH / 16;              // 32 rows per segment
    const int w  = wt * 32 + col;
    const int h0 = seg * SEGH;
    const float2* dg = defgrad + (size_t)b * HH * WW;

    float vals[SEGH];
    float s = 0.f;
#pragma unroll
    for (int i = 0; i < SEGH; ++i) {
        float v = dg[(size_t)(h0 + i) * WW + w].y;
        v = 2.0f / (1.0f + expf(-v));      // c/(1+(c-1)e^{-x}), c=2
        vals[i] = v;
        s += v;
    }

    __shared__ float part[16][32];
    part[seg][col] = s;
    __syncthreads();

    float run = 0.f;
    for (int j = 0; j < seg; ++j) run += part[j][col];   // exclusive seg prefix

    const size_t rowbase = ((size_t)b * HH + h0) * WW + w;
#pragma unroll
    for (int i = 0; i < SEGH; ++i) {
        run += vals[i];
        ys[(rowbase + (size_t)i * WW) * (size_t)ys_stride] = run;
    }
}

// ---------------------------------------------------------------------------
// Kernel 2: per-row fused — x_s row scan + residual affine + bilinear sample.
// grid: BB*HH blocks (one per image row); block: 512 threads (one per column).
// ---------------------------------------------------------------------------
__global__ __launch_bounds__(512)
void rowscan_sample_kernel(const float4* __restrict__ im4,
                           const float2* __restrict__ defgrad,
                           const float*  __restrict__ affine,
                           const float*  __restrict__ ys, int ys_stride,
                           float4* __restrict__ out4,
                           float*  __restrict__ grid3) {
    const int h = blockIdx.x % HH;
    const int b = blockIdx.x / HH;
    const int w = threadIdx.x;             // 0..511
    const size_t pix = ((size_t)b * HH + h) * WW + w;

    // logistic of x-deformation component
    float vx  = defgrad[pix].x;
    float dgx = 2.0f / (1.0f + expf(-vx));

    // inclusive scan across the 512-thread block (wave scan + LDS combine)
    const int lane = w & 63;
    const int wv   = w >> 6;               // 0..7
    float x = dgx;
#pragma unroll
    for (int off = 1; off < 64; off <<= 1) {
        float n = __shfl_up(x, off, 64);
        if (lane >= off) x += n;
    }
    __shared__ float wsum[8];
    if (lane == 63) wsum[wv] = x;
    __syncthreads();
    float pref = 0.f;
    for (int j = 0; j < wv; ++j) pref += wsum[j];
    const float xs = x + pref;

    const float ysv = ys[pix * (size_t)ys_stride];

    // residual affine (A = affine + I), row-major 3x3; out_j = A[j]·[xs,ys,1]
    const float* Ab = affine + b * 9;
    const float xg = (Ab[0] + 1.f) * xs + Ab[1] * ysv + Ab[2];
    const float yg = Ab[3] * xs + (Ab[4] + 1.f) * ysv + Ab[5];
    const float wg = Ab[6] * xs + Ab[7] * ysv + (Ab[8] + 1.f);

    // bilinear sampling, clamped corner indices exactly as reference
    const int ix = (int)floorf(xg);
    const int iy = (int)floorf(yg);
    const int x0 = min(max(ix,     0), WW - 1);
    const int x1 = min(max(ix + 1, 0), WW - 1);
    const int y0 = min(max(iy,     0), HH - 1);
    const int y1 = min(max(iy + 1, 0), HH - 1);
    const float x0f = (float)x0, x1f = (float)x1;
    const float y0f = (float)y0, y1f = (float)y1;
    const float wa = (x1f - xg) * (y1f - yg);
    const float wb = (x1f - xg) * (yg - y0f);
    const float wc = (xg - x0f) * (y1f - yg);
    const float wd = (xg - x0f) * (yg - y0f);

    const size_t base = (size_t)b * HH * WW;
    const float4 Ia = im4[base + (size_t)y0 * WW + x0];
    const float4 Ib = im4[base + (size_t)y1 * WW + x0];
    const float4 Ic = im4[base + (size_t)y0 * WW + x1];
    const float4 Id = im4[base + (size_t)y1 * WW + x1];

    float4 o;
    o.x = wa * Ia.x + wb * Ib.x + wc * Ic.x + wd * Id.x;
    o.y = wa * Ia.y + wb * Ib.y + wc * Ic.y + wd * Id.y;
    o.z = wa * Ia.z + wb * Ib.z + wc * Ic.z + wd * Id.z;
    o.w = wa * Ia.w + wb * Ib.w + wc * Ic.w + wd * Id.w;
    out4[pix] = o;

    // grid3 output (this thread owns grid3[3*pix .. 3*pix+2]; in the fallback
    // path grid3[3*pix+1] held ysv, already consumed above — safe to clobber)
    grid3[pix * 3 + 0] = xg;
    grid3[pix * 3 + 1] = yg;
    grid3[pix * 3 + 2] = wg;
}

extern "C" void kernel_launch(void* const* d_in, const int* in_sizes, int n_in,
                              void* d_out, int out_size, void* d_ws, size_t ws_size,
                              hipStream_t stream) {
    const float* im      = (const float*)d_in[0];
    const float* defgrad = (const float*)d_in[1];
    const float* affine  = (const float*)d_in[2];

    float* out   = (float*)d_out;
    float* grid3 = out + (size_t)BB * HH * WW * CC;

    const size_t ys_bytes = (size_t)BB * HH * WW * sizeof(float);
    float* ys;
    int ys_stride;
    if (ws_size >= ys_bytes) {             // planar scratch (preferred)
        ys = (float*)d_ws;
        ys_stride = 1;
    } else {                               // stash in grid3[...,1] slot (race-free)
        ys = grid3 + 1;
        ys_stride = 3;
    }

    colscan_kernel<<<BB * (WW / 32), 512, 0, stream>>>(
        (const float2*)defgrad, ys, ys_stride);

    rowscan_sample_kernel<<<BB * HH, 512, 0, stream>>>(
        (const float4*)im, (const float2*)defgrad, affine,
        ys, ys_stride, (float4*)out, grid3);
}